// Round 3
// baseline (142.060 us; speedup 1.0000x reference)
//
#include <hip/hip_runtime.h>

#define NBLOCKS 2048
#define TPB 256

typedef float f32x4 __attribute__((ext_vector_type(4)));

// Per-wave (64-lane) + per-block reduction of a double. Result valid in thread 0.
__device__ __forceinline__ double block_reduce_d(double x) {
    #pragma unroll
    for (int off = 32; off > 0; off >>= 1)
        x += __shfl_down(x, off, 64);
    __shared__ double lds[TPB / 64];
    const int lane = threadIdx.x & 63;
    const int wid  = threadIdx.x >> 6;
    if (lane == 0) lds[wid] = x;
    __syncthreads();
    if (wid == 0) {
        x = (lane < (TPB / 64)) ? lds[lane] : 0.0;
        #pragma unroll
        for (int off = (TPB / 128); off > 0; off >>= 1)
            x += __shfl_down(x, off, 64);
    }
    return x;
}

__device__ __forceinline__ float row_loss(const f32x4& a, const f32x4& b, int t) {
    float v[8] = {a.x, a.y, a.z, a.w, b.x, b.y, b.z, b.w};
    // max + first-index argmax (matches jnp.argmax tie-break via strict >)
    float m = v[0];
    int  am = 0;
    #pragma unroll
    for (int j = 1; j < 8; ++j)
        if (v[j] > m) { m = v[j]; am = j; }
    // sum of exp + branchless select of v[target] (static indexing only)
    float s = 0.f, vt = 0.f;
    #pragma unroll
    for (int j = 0; j < 8; ++j) {
        s += __expf(v[j] - m);
        vt = (j == t) ? v[j] : vt;
    }
    const float ce = -(vt - m - __logf(s));
    int d = t - am; d = (d < 0) ? -d : d;
    return ce * (1.0f + (float)d);
}

__global__ __launch_bounds__(TPB) void hrl_fused(
    const float*    __restrict__ pred,     // [batch, 8]
    const int*      __restrict__ tgt,      // [batch]
    double*         __restrict__ partial,  // [NBLOCKS]
    unsigned int*   __restrict__ counter,  // zeroed via hipMemsetAsync each call
    float*          __restrict__ out,      // [1]
    int batch, double inv_batch)
{
    const int tid    = blockIdx.x * TPB + threadIdx.x;
    const int stride = gridDim.x * TPB;

    double acc = 0.0;
    int i = tid;
    // Unroll x4: batch all loads first for memory-level parallelism.
    for (; i + 3 * stride < batch; i += 4 * stride) {
        f32x4 A[4], B[4];
        int   T[4];
        #pragma unroll
        for (int u = 0; u < 4; ++u) {
            const f32x4* p = reinterpret_cast<const f32x4*>(pred)
                             + (size_t)(i + u * stride) * 2;
            A[u] = __builtin_nontemporal_load(p);
            B[u] = __builtin_nontemporal_load(p + 1);
            T[u] = __builtin_nontemporal_load(tgt + i + u * stride);
        }
        float s4 = 0.f;
        #pragma unroll
        for (int u = 0; u < 4; ++u)
            s4 += row_loss(A[u], B[u], T[u]);
        acc += (double)s4;
    }
    // Remainder rows.
    for (; i < batch; i += stride) {
        const f32x4* p = reinterpret_cast<const f32x4*>(pred) + (size_t)i * 2;
        const f32x4 a = __builtin_nontemporal_load(p);
        const f32x4 b = __builtin_nontemporal_load(p + 1);
        acc += (double)row_loss(a, b, tgt[i]);
    }

    const double bsum = block_reduce_d(acc);

    // Last-block-done final reduction (deterministic: fixed summation order).
    __shared__ bool isLast;
    if (threadIdx.x == 0) {
        partial[blockIdx.x] = bsum;
        __threadfence();
        const unsigned int prev = atomicAdd(counter, 1u);
        isLast = (prev == gridDim.x - 1);
    }
    __syncthreads();
    if (isLast) {
        __threadfence();  // acquire: make all partial[] writes visible
        double s = 0.0;
        for (int k = threadIdx.x; k < (int)gridDim.x; k += TPB)
            s += partial[k];
        const double tot = block_reduce_d(s);
        if (threadIdx.x == 0) out[0] = (float)(tot * inv_batch);
    }
}

extern "C" void kernel_launch(void* const* d_in, const int* in_sizes, int n_in,
                              void* d_out, int out_size, void* d_ws, size_t ws_size,
                              hipStream_t stream) {
    const float* pred = (const float*)d_in[0];
    const int*   tgt  = (const int*)d_in[1];
    float* out = (float*)d_out;

    double*       partial = (double*)d_ws;
    unsigned int* counter = (unsigned int*)((char*)d_ws + NBLOCKS * sizeof(double));

    const int batch = in_sizes[0] / 8;  // predictions is [batch, 8]

    (void)hipMemsetAsync(counter, 0, sizeof(unsigned int), stream);
    hrl_fused<<<NBLOCKS, TPB, 0, stream>>>(pred, tgt, partial, counter, out,
                                           batch, 1.0 / (double)batch);
}

// Round 4
// 100.969 us; speedup vs baseline: 1.4070x; 1.4070x over previous
//
#include <hip/hip_runtime.h>

#define NBLOCKS 2048
#define TPB 256

typedef float f32x4 __attribute__((ext_vector_type(4)));

// Per-wave (64-lane) + per-block reduction of a double. Result valid in thread 0.
__device__ __forceinline__ double block_reduce_d(double x) {
    #pragma unroll
    for (int off = 32; off > 0; off >>= 1)
        x += __shfl_down(x, off, 64);
    __shared__ double lds[TPB / 64];
    const int lane = threadIdx.x & 63;
    const int wid  = threadIdx.x >> 6;
    if (lane == 0) lds[wid] = x;
    __syncthreads();
    if (wid == 0) {
        x = (lane < (TPB / 64)) ? lds[lane] : 0.0;
        #pragma unroll
        for (int off = (TPB / 128); off > 0; off >>= 1)
            x += __shfl_down(x, off, 64);
    }
    return x;
}

__device__ __forceinline__ float row_loss(const f32x4& a, const f32x4& b, int t) {
    float v[8] = {a.x, a.y, a.z, a.w, b.x, b.y, b.z, b.w};
    // max + first-index argmax (matches jnp.argmax tie-break via strict >)
    float m = v[0];
    int  am = 0;
    #pragma unroll
    for (int j = 1; j < 8; ++j)
        if (v[j] > m) { m = v[j]; am = j; }
    // sum of exp + branchless select of v[target] (static indexing only)
    float s = 0.f, vt = 0.f;
    #pragma unroll
    for (int j = 0; j < 8; ++j) {
        s += __expf(v[j] - m);
        vt = (j == t) ? v[j] : vt;
    }
    const float ce = -(vt - m - __logf(s));
    int d = t - am; d = (d < 0) ? -d : d;
    return ce * (1.0f + (float)d);
}

__global__ __launch_bounds__(TPB) void hrl_fused(
    const float*    __restrict__ pred,     // [batch, 8]
    const int*      __restrict__ tgt,      // [batch]
    double*         __restrict__ partial,  // [NBLOCKS]
    unsigned int*   __restrict__ counter,  // zeroed via hipMemsetAsync each call
    float*          __restrict__ out,      // [1]
    int batch, double inv_batch)
{
    const int tid    = blockIdx.x * TPB + threadIdx.x;
    const int stride = gridDim.x * TPB;

    double acc = 0.0;
    int i = tid;
    // Unroll x4: batch all loads first for memory-level parallelism.
    // Plain cached loads — nt loads bypass L2/L3 and were a 4x regression (R3).
    for (; i + 3 * stride < batch; i += 4 * stride) {
        f32x4 A[4], B[4];
        int   T[4];
        #pragma unroll
        for (int u = 0; u < 4; ++u) {
            const f32x4* p = reinterpret_cast<const f32x4*>(pred)
                             + (size_t)(i + u * stride) * 2;
            A[u] = p[0];
            B[u] = p[1];
            T[u] = tgt[i + u * stride];
        }
        float s4 = 0.f;
        #pragma unroll
        for (int u = 0; u < 4; ++u)
            s4 += row_loss(A[u], B[u], T[u]);
        acc += (double)s4;
    }
    // Remainder rows.
    for (; i < batch; i += stride) {
        const f32x4* p = reinterpret_cast<const f32x4*>(pred) + (size_t)i * 2;
        acc += (double)row_loss(p[0], p[1], tgt[i]);
    }

    const double bsum = block_reduce_d(acc);

    // Last-block-done final reduction (deterministic: fixed summation order).
    __shared__ bool isLast;
    if (threadIdx.x == 0) {
        partial[blockIdx.x] = bsum;
        __threadfence();
        const unsigned int prev = atomicAdd(counter, 1u);
        isLast = (prev == gridDim.x - 1);
    }
    __syncthreads();
    if (isLast) {
        __threadfence();  // acquire: make all partial[] writes visible
        double s = 0.0;
        for (int k = threadIdx.x; k < (int)gridDim.x; k += TPB)
            s += partial[k];
        const double tot = block_reduce_d(s);
        if (threadIdx.x == 0) out[0] = (float)(tot * inv_batch);
    }
}

extern "C" void kernel_launch(void* const* d_in, const int* in_sizes, int n_in,
                              void* d_out, int out_size, void* d_ws, size_t ws_size,
                              hipStream_t stream) {
    const float* pred = (const float*)d_in[0];
    const int*   tgt  = (const int*)d_in[1];
    float* out = (float*)d_out;

    double*       partial = (double*)d_ws;
    unsigned int* counter = (unsigned int*)((char*)d_ws + NBLOCKS * sizeof(double));

    const int batch = in_sizes[0] / 8;  // predictions is [batch, 8]

    (void)hipMemsetAsync(counter, 0, sizeof(unsigned int), stream);
    hrl_fused<<<NBLOCKS, TPB, 0, stream>>>(pred, tgt, partial, counter, out,
                                           batch, 1.0 / (double)batch);
}

// Round 5
// 99.575 us; speedup vs baseline: 1.4267x; 1.0140x over previous
//
#include <hip/hip_runtime.h>

#define NBLOCKS 2048
#define TPB 256

typedef float f32x4 __attribute__((ext_vector_type(4)));

// Per-wave (64-lane) + per-block reduction of a double. Result valid in thread 0.
__device__ __forceinline__ double block_reduce_d(double x) {
    #pragma unroll
    for (int off = 32; off > 0; off >>= 1)
        x += __shfl_down(x, off, 64);
    __shared__ double lds[TPB / 64];
    const int lane = threadIdx.x & 63;
    const int wid  = threadIdx.x >> 6;
    if (lane == 0) lds[wid] = x;
    __syncthreads();
    if (wid == 0) {
        x = (lane < (TPB / 64)) ? lds[lane] : 0.0;
        #pragma unroll
        for (int off = (TPB / 128); off > 0; off >>= 1)
            x += __shfl_down(x, off, 64);
    }
    return x;
}

__global__ __launch_bounds__(TPB) void hrl_fused(
    const float*    __restrict__ pred,     // [batch, 8]
    const int*      __restrict__ tgt,      // [batch]
    double*         __restrict__ partial,  // [NBLOCKS]
    unsigned int*   __restrict__ counter,  // zeroed via hipMemsetAsync each call
    float*          __restrict__ out,      // [1]
    int batch, double inv_batch)
{
    const int tid    = blockIdx.x * TPB + threadIdx.x;
    const int stride = gridDim.x * TPB;

    // EXACT R1 main loop (proven 33.5us total) — do not restructure.
    // R4's batched x4 unroll regressed 3x (compiler refused to materialize
    // the load arrays: VGPR=28 < needed 40).
    double acc = 0.0;
    for (int i = tid; i < batch; i += stride) {
        const f32x4* p = reinterpret_cast<const f32x4*>(pred) + (size_t)i * 2;
        const f32x4 a = p[0];
        const f32x4 b = p[1];
        float v[8] = {a.x, a.y, a.z, a.w, b.x, b.y, b.z, b.w};

        // max + first-index argmax (matches jnp.argmax tie-break via strict >)
        float m = v[0];
        int  am = 0;
        #pragma unroll
        for (int j = 1; j < 8; ++j) {
            if (v[j] > m) { m = v[j]; am = j; }
        }

        // sum of exp, and branchless select of v[target] (static indexing only)
        const int t = tgt[i];
        float s  = 0.f;
        float vt = 0.f;
        #pragma unroll
        for (int j = 0; j < 8; ++j) {
            s += __expf(v[j] - m);
            vt = (j == t) ? v[j] : vt;
        }

        const float ce  = -(vt - m - __logf(s));
        int d = t - am; d = (d < 0) ? -d : d;
        acc += (double)(ce * (1.0f + (float)d));
    }

    const double bsum = block_reduce_d(acc);

    // Fused final reduction: last-block-done (deterministic summation order).
    __shared__ bool isLast;
    if (threadIdx.x == 0) {
        partial[blockIdx.x] = bsum;
        __threadfence();
        const unsigned int prev = atomicAdd(counter, 1u);
        isLast = (prev == gridDim.x - 1);
    }
    __syncthreads();
    if (isLast) {
        __threadfence();  // acquire: make all partial[] writes visible
        double s = 0.0;
        for (int k = threadIdx.x; k < (int)gridDim.x; k += TPB)
            s += partial[k];
        const double tot = block_reduce_d(s);
        if (threadIdx.x == 0) out[0] = (float)(tot * inv_batch);
    }
}

extern "C" void kernel_launch(void* const* d_in, const int* in_sizes, int n_in,
                              void* d_out, int out_size, void* d_ws, size_t ws_size,
                              hipStream_t stream) {
    const float* pred = (const float*)d_in[0];
    const int*   tgt  = (const int*)d_in[1];
    float* out = (float*)d_out;

    double*       partial = (double*)d_ws;
    unsigned int* counter = (unsigned int*)((char*)d_ws + NBLOCKS * sizeof(double));

    const int batch = in_sizes[0] / 8;  // predictions is [batch, 8]

    (void)hipMemsetAsync(counter, 0, sizeof(unsigned int), stream);
    hrl_fused<<<NBLOCKS, TPB, 0, stream>>>(pred, tgt, partial, counter, out,
                                           batch, 1.0 / (double)batch);
}

// Round 6
// 33.178 us; speedup vs baseline: 4.2817x; 3.0012x over previous
//
#include <hip/hip_runtime.h>

#define NBLOCKS 2048
#define TPB 256

typedef float f32x4 __attribute__((ext_vector_type(4)));

// Per-wave (64-lane) + per-block reduction of a double. Result valid in thread 0.
__device__ __forceinline__ double block_reduce_d(double x) {
    #pragma unroll
    for (int off = 32; off > 0; off >>= 1)
        x += __shfl_down(x, off, 64);
    __shared__ double lds[TPB / 64];
    const int lane = threadIdx.x & 63;
    const int wid  = threadIdx.x >> 6;
    if (lane == 0) lds[wid] = x;
    __syncthreads();
    if (wid == 0) {
        x = (lane < (TPB / 64)) ? lds[lane] : 0.0;
        #pragma unroll
        for (int off = (TPB / 128); off > 0; off >>= 1)
            x += __shfl_down(x, off, 64);
    }
    return x;
}

__device__ __forceinline__ float row_loss(f32x4 a, f32x4 b, int t) {
    float v[8] = {a.x, a.y, a.z, a.w, b.x, b.y, b.z, b.w};
    // max + first-index argmax (matches jnp.argmax tie-break via strict >)
    float m = v[0];
    int  am = 0;
    #pragma unroll
    for (int j = 1; j < 8; ++j)
        if (v[j] > m) { m = v[j]; am = j; }
    // sum of exp + branchless select of v[target] (static indexing only)
    float s = 0.f, vt = 0.f;
    #pragma unroll
    for (int j = 0; j < 8; ++j) {
        s += __expf(v[j] - m);
        vt = (j == t) ? v[j] : vt;
    }
    const float ce = -(vt - m - __logf(s));
    int d = t - am; d = (d < 0) ? -d : d;
    return ce * (1.0f + (float)d);
}

// Two-kernel structure (R1, proven 33.5us). The fused last-block-done epilogue
// with __threadfence + single-line atomicAdd costs ~70-120us on MI355X
// (cross-XCD L2 coherence) — do NOT fuse the final reduction.
__global__ __launch_bounds__(TPB) void hrl_partial(
    const float* __restrict__ pred,   // [batch, 8]
    const int*   __restrict__ tgt,    // [batch]
    double*      __restrict__ partial,// [NBLOCKS]
    int batch)
{
    const int tid    = blockIdx.x * TPB + threadIdx.x;
    const int stride = gridDim.x * TPB;

    double acc = 0.0;
    int i = tid;
    // Two independent row streams per iteration (named scalars, no arrays)
    // for memory-level parallelism.
    for (; i + stride < batch; i += 2 * stride) {
        const f32x4* p0 = reinterpret_cast<const f32x4*>(pred) + (size_t)i * 2;
        const f32x4* p1 = reinterpret_cast<const f32x4*>(pred) + (size_t)(i + stride) * 2;
        const f32x4 a0 = p0[0];
        const f32x4 b0 = p0[1];
        const f32x4 a1 = p1[0];
        const f32x4 b1 = p1[1];
        const int   t0 = tgt[i];
        const int   t1 = tgt[i + stride];
        acc += (double)(row_loss(a0, b0, t0) + row_loss(a1, b1, t1));
    }
    for (; i < batch; i += stride) {
        const f32x4* p = reinterpret_cast<const f32x4*>(pred) + (size_t)i * 2;
        acc += (double)row_loss(p[0], p[1], tgt[i]);
    }

    const double bsum = block_reduce_d(acc);
    if (threadIdx.x == 0) partial[blockIdx.x] = bsum;  // overwrite: deterministic
}

__global__ __launch_bounds__(TPB) void hrl_final(
    const double* __restrict__ partial,
    float*        __restrict__ out,
    int nparts, double inv_batch)
{
    double s = 0.0;
    for (int i = threadIdx.x; i < nparts; i += TPB)
        s += partial[i];
    const double tot = block_reduce_d(s);
    if (threadIdx.x == 0) out[0] = (float)(tot * inv_batch);
}

extern "C" void kernel_launch(void* const* d_in, const int* in_sizes, int n_in,
                              void* d_out, int out_size, void* d_ws, size_t ws_size,
                              hipStream_t stream) {
    const float* pred = (const float*)d_in[0];
    const int*   tgt  = (const int*)d_in[1];
    float*  out = (float*)d_out;
    double* ws  = (double*)d_ws;

    const int batch = in_sizes[0] / 8;  // predictions is [batch, 8]

    hrl_partial<<<NBLOCKS, TPB, 0, stream>>>(pred, tgt, ws, batch);
    hrl_final<<<1, TPB, 0, stream>>>(ws, out, NBLOCKS, 1.0 / (double)batch);
}

// Round 7
// 31.981 us; speedup vs baseline: 4.4420x; 1.0374x over previous
//
#include <hip/hip_runtime.h>

#define NBLOCKS 2048
#define TPB 256

typedef float f32x4 __attribute__((ext_vector_type(4)));

// Per-wave (64-lane) + per-block reduction of a double. Result valid in thread 0.
__device__ __forceinline__ double block_reduce_d(double x) {
    #pragma unroll
    for (int off = 32; off > 0; off >>= 1)
        x += __shfl_down(x, off, 64);
    __shared__ double lds[TPB / 64];
    const int lane = threadIdx.x & 63;
    const int wid  = threadIdx.x >> 6;
    if (lane == 0) lds[wid] = x;
    __syncthreads();
    if (wid == 0) {
        x = (lane < (TPB / 64)) ? lds[lane] : 0.0;
        #pragma unroll
        for (int off = (TPB / 128); off > 0; off >>= 1)
            x += __shfl_down(x, off, 64);
    }
    return x;
}

// Lane-pair cooperative kernel: lanes 2k,2k+1 co-own one row.
// Each lane loads exactly one float4 -> 16B/lane contiguous across the wave
// (the coalescing ideal), vs. the 32B-strided whole-row-per-lane pattern.
__global__ __launch_bounds__(TPB) void hrl_partial(
    const float* __restrict__ pred,   // [batch, 8]
    const int*   __restrict__ tgt,    // [batch]
    double*      __restrict__ partial,// [NBLOCKS]
    int batch)
{
    const int lane = threadIdx.x & 63;
    const int half = lane & 1;        // which half-row I hold (levels 4h..4h+3)
    const int pair = lane >> 1;       // 0..31: row slot within the wave
    const int gwave  = (blockIdx.x * TPB + threadIdx.x) >> 6;
    const int nwaves = (NBLOCKS * TPB) >> 6;

    double acc = 0.0;
    for (int base = gwave * 32; base < batch; base += nwaves * 32) {
        const int r = base + pair;
        if (r < batch) {
            const f32x4 v = *(reinterpret_cast<const f32x4*>(pred) + (size_t)r * 2 + half);
            const int   t = tgt[r];

            // local max + first-index argmax over my 4 (absolute index)
            float m4 = v.x; int a4 = 0;
            if (v.y > m4) { m4 = v.y; a4 = 1; }
            if (v.z > m4) { m4 = v.z; a4 = 2; }
            if (v.w > m4) { m4 = v.w; a4 = 3; }
            a4 += half * 4;

            // combine with partner lane; ties go to the lower index (jnp.argmax)
            const float om = __shfl_xor(m4, 1, 64);
            const int   oa = __shfl_xor(a4, 1, 64);
            const float mlo = half ? om : m4;
            const float mhi = half ? m4 : om;
            const int   alo = half ? oa : a4;
            const int   ahi = half ? a4 : oa;
            const float m  = fmaxf(mlo, mhi);
            const int   am = (mhi > mlo) ? ahi : alo;

            // exp-sum (partner-combined)
            float s4 = __expf(v.x - m) + __expf(v.y - m)
                     + __expf(v.z - m) + __expf(v.w - m);
            const float s = s4 + __shfl_xor(s4, 1, 64);

            // v[target]: exactly one lane of the pair contributes
            const int tb = t - half * 4;   // 0..3 if target in my half
            float vt4 = 0.f;
            vt4 = (tb == 0) ? v.x : vt4;
            vt4 = (tb == 1) ? v.y : vt4;
            vt4 = (tb == 2) ? v.z : vt4;
            vt4 = (tb == 3) ? v.w : vt4;
            const float vt = vt4 + __shfl_xor(vt4, 1, 64);

            const float ce = -(vt - m - __logf(s));
            int d = t - am; d = (d < 0) ? -d : d;
            // both lanes add half the loss (x0.5 is exact in double)
            acc += (double)(ce * (1.0f + (float)d)) * 0.5;
        }
    }

    const double bsum = block_reduce_d(acc);
    if (threadIdx.x == 0) partial[blockIdx.x] = bsum;  // overwrite: deterministic
}

__global__ __launch_bounds__(TPB) void hrl_final(
    const double* __restrict__ partial,
    float*        __restrict__ out,
    int nparts, double inv_batch)
{
    double s = 0.0;
    for (int i = threadIdx.x; i < nparts; i += TPB)
        s += partial[i];
    const double tot = block_reduce_d(s);
    if (threadIdx.x == 0) out[0] = (float)(tot * inv_batch);
}

extern "C" void kernel_launch(void* const* d_in, const int* in_sizes, int n_in,
                              void* d_out, int out_size, void* d_ws, size_t ws_size,
                              hipStream_t stream) {
    const float* pred = (const float*)d_in[0];
    const int*   tgt  = (const int*)d_in[1];
    float*  out = (float*)d_out;
    double* ws  = (double*)d_ws;

    const int batch = in_sizes[0] / 8;  // predictions is [batch, 8]

    hrl_partial<<<NBLOCKS, TPB, 0, stream>>>(pred, tgt, ws, batch);
    hrl_final<<<1, TPB, 0, stream>>>(ws, out, NBLOCKS, 1.0 / (double)batch);
}